// Round 3
// baseline (1066.669 us; speedup 1.0000x reference)
//
#include <hip/hip_runtime.h>
#include <hip/hip_bf16.h>
#include <stdint.h>

#define B_ 16
#define N_ 64
#define S_ 4096
#define C_ 384
#define H_ 6
#define DH_ 64
#define SCALE_ 0.125f
#define TAU_ 2e-4f
#define LISTCAP 262144

typedef __attribute__((ext_vector_type(8))) short bf16x8;
typedef __attribute__((ext_vector_type(4))) float f32x4;

static __device__ __forceinline__ unsigned short f2bf(float x) {
    union { float f; unsigned u; } v; v.f = x;
    unsigned r = v.u + 0x7FFFu + ((v.u >> 16) & 1u);
    return (unsigned short)(r >> 16);
}
static __device__ __forceinline__ float bf2f(unsigned short b) {
    union { unsigned u; float f; } v; v.u = ((unsigned)b) << 16; return v.f;
}

// async global->LDS, 16B/lane; LDS dest = wave-uniform base + lane*16
static __device__ __forceinline__ void gl_lds16(const void* g, void* l) {
    __builtin_amdgcn_global_load_lds(
        (const __attribute__((address_space(1))) unsigned int*)g,
        (__attribute__((address_space(3))) unsigned int*)l, 16, 0, 0);
}

// ---------------------------------------------------------------------------
// K0: prep — key -> khi/klo (bf16 hi + bf16 residual), Wv -> bf16
// ---------------------------------------------------------------------------
__global__ __launch_bounds__(256) void prep_kernel(const float* __restrict__ key,
                                                   const float* __restrict__ Wv,
                                                   unsigned short* __restrict__ khi,
                                                   unsigned short* __restrict__ klo,
                                                   unsigned short* __restrict__ wvb) {
    size_t gid = (size_t)blockIdx.x * 256 + threadIdx.x;
    const size_t nkey8 = (size_t)B_ * S_ * C_ / 8;
    if (gid < nkey8) {
        size_t base = gid * 8;
        float4 x0 = *(const float4*)(key + base);
        float4 x1 = *(const float4*)(key + base + 4);
        float xs[8] = { x0.x, x0.y, x0.z, x0.w, x1.x, x1.y, x1.z, x1.w };
        unsigned short hi[8], lo[8];
#pragma unroll
        for (int i = 0; i < 8; ++i) {
            hi[i] = f2bf(xs[i]);
            lo[i] = f2bf(xs[i] - bf2f(hi[i]));
        }
        *(bf16x8*)(khi + base) = *(bf16x8*)hi;
        *(bf16x8*)(klo + base) = *(bf16x8*)lo;
    } else {
        size_t g2 = gid - nkey8;
        if (g2 < (size_t)C_ * C_ / 8) {
            size_t base = g2 * 8;
            float4 x0 = *(const float4*)(Wv + base);
            float4 x1 = *(const float4*)(Wv + base + 4);
            float xs[8] = { x0.x, x0.y, x0.z, x0.w, x1.x, x1.y, x1.z, x1.w };
            unsigned short hi[8];
#pragma unroll
            for (int i = 0; i < 8; ++i) hi[i] = f2bf(xs[i]);
            *(bf16x8*)(wvb + base) = *(bf16x8*)hi;
        }
    }
}

// ---------------------------------------------------------------------------
// K1: fused q-proj + qk. Block = (b, group of 8 n-rows), 384 threads.
// qk[b,h,n,c] = sum_d (SCALE * (query[b,n,:].Wq[h*64+d,:])) * Wk[h*64+d,c]
// Weights read once per 8 rows (vs once per row before).
// ---------------------------------------------------------------------------
__global__ __launch_bounds__(384) void qk_fused_kernel(const float* __restrict__ query,
                                                       const float* __restrict__ Wq,
                                                       const float* __restrict__ Wk,
                                                       float* __restrict__ qk,
                                                       unsigned short* __restrict__ qkhi,
                                                       unsigned short* __restrict__ qklo) {
    __shared__ float qstage[8][C_];
    __shared__ float qrow[8][C_];
    int ng = blockIdx.x, b = blockIdx.y;
    int t = threadIdx.x;
    int n0 = ng * 8;
#pragma unroll
    for (int i = 0; i < 8; ++i)
        qstage[i][t] = query[((size_t)(b * N_ + n0 + i)) * C_ + t];
    __syncthreads();
    {
        float a[8];
#pragma unroll
        for (int i = 0; i < 8; ++i) a[i] = 0.f;
        const float4* wq = (const float4*)(Wq + (size_t)t * C_);
        for (int c4 = 0; c4 < C_ / 4; ++c4) {
            float4 w = wq[c4];
#pragma unroll
            for (int i = 0; i < 8; ++i)
                a[i] += qstage[i][c4 * 4 + 0] * w.x + qstage[i][c4 * 4 + 1] * w.y
                      + qstage[i][c4 * 4 + 2] * w.z + qstage[i][c4 * 4 + 3] * w.w;
        }
#pragma unroll
        for (int i = 0; i < 8; ++i) qrow[i][t] = a[i] * SCALE_;
    }
    __syncthreads();
    for (int h = 0; h < H_; ++h) {
        float a[8];
#pragma unroll
        for (int i = 0; i < 8; ++i) a[i] = 0.f;
        const float* wk = Wk + (size_t)h * DH_ * C_ + t;
#pragma unroll 4
        for (int d = 0; d < DH_; ++d) {
            float w = wk[(size_t)d * C_];
#pragma unroll
            for (int i = 0; i < 8; ++i) a[i] += qrow[i][h * DH_ + d] * w;
        }
#pragma unroll
        for (int i = 0; i < 8; ++i) {
            size_t o = ((size_t)(b * H_ + h) * N_ + n0 + i) * C_ + t;
            float v = a[i];
            qk[o] = v;
            unsigned short hi = f2bf(v);
            qkhi[o] = hi;
            qklo[o] = f2bf(v - bf2f(hi));
        }
    }
}

// ---------------------------------------------------------------------------
// K2: logits via 3-pass bf16 MFMA + argmax. Tile 64n x 128 tokens, LDS 24KB,
// 6 blocks/CU target. XOR-swizzled LDS quarters: quarter q of row r stored at
// position q ^ ((r>>1)&3)  => b128 fragment reads are 2-way (free) not 8-way.
// ---------------------------------------------------------------------------
__global__ __launch_bounds__(256, 6) void attn_kernel(const unsigned short* __restrict__ qkhi,
                                                      const unsigned short* __restrict__ qklo,
                                                      const unsigned short* __restrict__ khi,
                                                      const unsigned short* __restrict__ klo,
                                                      unsigned int* __restrict__ idx,
                                                      unsigned int* __restrict__ flag_cnt,
                                                      unsigned int* __restrict__ flag_list) {
    __shared__ __align__(16) unsigned short sAhi[64 * 32];    // 4 KB
    __shared__ __align__(16) unsigned short sAlo[64 * 32];    // 4 KB
    __shared__ __align__(16) unsigned short sBhi[128 * 32];   // 8 KB
    __shared__ __align__(16) unsigned short sBlo[128 * 32];   // 8 KB
    int tid = threadIdx.x;
    int w = tid >> 6, l = tid & 63;
    int wm = w >> 1, wn = w & 1;
    int q4 = l >> 4, lm = l & 15;
    int s0 = blockIdx.x * 128;
    int h = blockIdx.y, b = blockIdx.z;
    size_t kbK = ((size_t)b * S_ + s0) * C_;
    size_t kbA = (size_t)(b * H_ + h) * N_ * C_;
    int trow16 = l >> 2;                              // staged row within 16-row block
    int tquart = ((l & 3) ^ ((l >> 3) & 3)) * 8;      // swizzled source quarter
    int sw = (q4 ^ ((lm >> 1) & 3)) * 8;              // swizzled read quarter

    f32x4 acc[2][4];
#pragma unroll
    for (int tm = 0; tm < 2; ++tm)
#pragma unroll
        for (int nt = 0; nt < 4; ++nt) acc[tm][nt] = (f32x4)0.f;

    for (int kc = 0; kc < C_; kc += 32) {
        __syncthreads();
#pragma unroll
        for (int i = 0; i < 6; ++i) {
            int gid = w * 6 + i;
            if (gid < 8) {
                gl_lds16(khi + kbK + (size_t)(gid * 16 + trow16) * C_ + kc + tquart,
                         (char*)sBhi + gid * 1024);
            } else if (gid < 16) {
                int g2 = gid - 8;
                gl_lds16(klo + kbK + (size_t)(g2 * 16 + trow16) * C_ + kc + tquart,
                         (char*)sBlo + g2 * 1024);
            } else if (gid < 20) {
                int g2 = gid - 16;
                gl_lds16(qkhi + kbA + (size_t)(g2 * 16 + trow16) * C_ + kc + tquart,
                         (char*)sAhi + g2 * 1024);
            } else {
                int g2 = gid - 20;
                gl_lds16(qklo + kbA + (size_t)(g2 * 16 + trow16) * C_ + kc + tquart,
                         (char*)sAlo + g2 * 1024);
            }
        }
        __syncthreads();
        bf16x8 ah[2], al[2];
#pragma unroll
        for (int tm = 0; tm < 2; ++tm) {
            int ar = (wm * 32 + tm * 16 + lm) * 32 + sw;
            ah[tm] = *(const bf16x8*)&sAhi[ar];
            al[tm] = *(const bf16x8*)&sAlo[ar];
        }
#pragma unroll
        for (int nt = 0; nt < 4; ++nt) {
            int nr = ((wn * 4 + nt) * 16 + lm) * 32 + sw;
            bf16x8 bh = *(const bf16x8*)&sBhi[nr];
            bf16x8 bl = *(const bf16x8*)&sBlo[nr];
#pragma unroll
            for (int tm = 0; tm < 2; ++tm) {
                acc[tm][nt] = __builtin_amdgcn_mfma_f32_16x16x32_bf16(ah[tm], bh, acc[tm][nt], 0, 0, 0);
                acc[tm][nt] = __builtin_amdgcn_mfma_f32_16x16x32_bf16(ah[tm], bl, acc[tm][nt], 0, 0, 0);
                acc[tm][nt] = __builtin_amdgcn_mfma_f32_16x16x32_bf16(al[tm], bh, acc[tm][nt], 0, 0, 0);
            }
        }
    }
    __syncthreads();

    float* rm1 = (float*)sBhi;            // [2][128]
    float* rm2 = rm1 + 256;
    int* ri1 = (int*)(rm2 + 256);
    int* ri2 = ri1 + 256;

#pragma unroll
    for (int nt = 0; nt < 4; ++nt) {
        float m1 = -3.4e38f, m2 = -3.4e38f; int i1 = 0, i2 = 0;
#pragma unroll
        for (int tm = 0; tm < 2; ++tm)
#pragma unroll
            for (int r = 0; r < 4; ++r) {
                float v = acc[tm][nt][r];
                int row = wm * 32 + tm * 16 + q4 * 4 + r;
                if (v > m1) { m2 = m1; i2 = i1; m1 = v; i1 = row; }
                else if (v > m2) { m2 = v; i2 = row; }
            }
#pragma unroll
        for (int off = 16; off < 64; off <<= 1) {
            float om1 = __shfl_xor(m1, off), om2 = __shfl_xor(m2, off);
            int oi1 = __shfl_xor(i1, off), oi2 = __shfl_xor(i2, off);
            bool take = (om1 > m1) || (om1 == m1 && oi1 < i1);
            float w1 = take ? om1 : m1; int wi1 = take ? oi1 : i1;
            float l1 = take ? m1 : om1; int li1 = take ? i1 : oi1;
            float s2 = m2; int si2 = i2;
            if (om2 > s2) { s2 = om2; si2 = oi2; }
            if (l1 > s2) { s2 = l1; si2 = li1; }
            m1 = w1; i1 = wi1; m2 = s2; i2 = si2;
        }
        if (q4 == 0) {
            int cw = (wn * 4 + nt) * 16 + lm;
            rm1[wm * 128 + cw] = m1; rm2[wm * 128 + cw] = m2;
            ri1[wm * 128 + cw] = i1; ri2[wm * 128 + cw] = i2;
        }
    }
    __syncthreads();
    if (tid < 128) {
        float a1 = rm1[tid], a2 = rm2[tid];
        int ai1 = ri1[tid], ai2 = ri2[tid];
        float b1 = rm1[128 + tid], b2 = rm2[128 + tid];
        int bi1 = ri1[128 + tid], bi2 = ri2[128 + tid];
        float w1, s2; int wi1, wi2;
        if (b1 > a1) { w1 = b1; wi1 = bi1; s2 = a1; wi2 = ai1; if (b2 > s2) { s2 = b2; wi2 = bi2; } }
        else         { w1 = a1; wi1 = ai1; s2 = a2; wi2 = ai2; if (b1 > s2) { s2 = b1; wi2 = bi1; } }
        idx[(size_t)(b * H_ + h) * S_ + s0 + tid] = (unsigned)wi1;
        if (w1 - s2 < TAU_) {
            unsigned p = atomicAdd(flag_cnt, 1u);
            if (p < LISTCAP) {
                unsigned tok = (unsigned)((b * H_ + h) * S_ + s0 + tid);
                flag_list[p] = tok | ((unsigned)wi1 << 19) | ((unsigned)wi2 << 25);
            }
        }
    }
}

// ---------------------------------------------------------------------------
// K3: fixup — exact fp32 recompute of two candidate rows for near-ties
// ---------------------------------------------------------------------------
__global__ __launch_bounds__(256) void fixup_kernel(const float* __restrict__ qk,
                                                    const float* __restrict__ key,
                                                    const unsigned int* __restrict__ flag_list,
                                                    const unsigned int* __restrict__ flag_cnt,
                                                    unsigned int* __restrict__ idx) {
    int w = threadIdx.x >> 6, l = threadIdx.x & 63;
    unsigned total = flag_cnt[0];
    if (total > LISTCAP) total = LISTCAP;
    for (unsigned t = blockIdx.x * 4 + w; t < total; t += gridDim.x * 4) {
        unsigned e = flag_list[t];
        unsigned tok = e & 0x7FFFFu;
        int i1 = (int)((e >> 19) & 63u), i2 = (int)((e >> 25) & 63u);
        unsigned bh = tok >> 12;
        unsigned s = tok & 4095u;
        unsigned bb = bh / H_;
        int l32 = l & 31;
        const float* qrow = qk + ((size_t)bh * N_ + (l < 32 ? i1 : i2)) * C_ + l32 * 12;
        const float* krow = key + ((size_t)bb * S_ + s) * C_ + l32 * 12;
        float sum = 0.f;
#pragma unroll
        for (int c = 0; c < 12; ++c) sum += qrow[c] * krow[c];
#pragma unroll
        for (int off = 1; off < 32; off <<= 1) sum += __shfl_xor(sum, off);
        float d1 = __shfl(sum, 0);
        float d2 = __shfl(sum, 32);
        int win = (d2 > d1 || (d2 == d1 && i2 < i1)) ? i2 : i1;
        if (l == 0) idx[(size_t)bh * S_ + s] = (unsigned)win;
    }
}

// ---------------------------------------------------------------------------
// K4: v projection, bf16 MFMA, XOR-swizzled LDS. Output HEAD-MAJOR:
// vb[((b*H+h)*S + s)*DH + d]
// ---------------------------------------------------------------------------
__global__ __launch_bounds__(256) void vproj_kernel(const unsigned short* __restrict__ khi,
                                                    const unsigned short* __restrict__ wvb,
                                                    unsigned short* __restrict__ vb) {
    __shared__ __align__(16) unsigned short sA[64 * 32];
    __shared__ __align__(16) unsigned short sB[C_ * 32];
    int tid = threadIdx.x;
    size_t m0 = (size_t)blockIdx.x * 64;
    int bb = (int)(m0 >> 12);            // batch
    int sbase = (int)(m0 & (S_ - 1));    // token base within batch
    int w = tid >> 6, l = tid & 63;
    int wm = w >> 1, wn = w & 1;
    int q4 = l >> 4, lm = l & 15;
    int trow16 = l >> 2;
    int tquart = ((l & 3) ^ ((l >> 3) & 3)) * 8;
    int sw = (q4 ^ ((lm >> 1) & 3)) * 8;

    f32x4 accv[6][2][2];
#pragma unroll
    for (int j = 0; j < 6; ++j)
#pragma unroll
        for (int tm = 0; tm < 2; ++tm)
#pragma unroll
            for (int tn = 0; tn < 2; ++tn) accv[j][tm][tn] = (f32x4)0.f;

    for (int kc = 0; kc < C_; kc += 32) {
        __syncthreads();
#pragma unroll
        for (int i = 0; i < 7; ++i) {
            int gid = w * 7 + i;
            if (gid < 24) {
                gl_lds16(wvb + (size_t)(gid * 16 + trow16) * C_ + kc + tquart,
                         (char*)sB + gid * 1024);
            } else {
                int g2 = gid - 24;
                gl_lds16(khi + (m0 + g2 * 16 + trow16) * C_ + kc + tquart,
                         (char*)sA + g2 * 1024);
            }
        }
        __syncthreads();
        bf16x8 af[2], bfr[6][2];
#pragma unroll
        for (int tm = 0; tm < 2; ++tm)
            af[tm] = *(const bf16x8*)&sA[(wm * 32 + tm * 16 + lm) * 32 + sw];
#pragma unroll
        for (int j = 0; j < 6; ++j)
#pragma unroll
            for (int tn = 0; tn < 2; ++tn)
                bfr[j][tn] = *(const bf16x8*)&sB[(j * 64 + wn * 32 + tn * 16 + lm) * 32 + sw];
#pragma unroll
        for (int j = 0; j < 6; ++j)
#pragma unroll
            for (int tm = 0; tm < 2; ++tm)
#pragma unroll
                for (int tn = 0; tn < 2; ++tn)
                    accv[j][tm][tn] = __builtin_amdgcn_mfma_f32_16x16x32_bf16(
                        af[tm], bfr[j][tn], accv[j][tm][tn], 0, 0, 0);
    }
    int drow = (l >> 4) * 4, dcol = l & 15;
#pragma unroll
    for (int j = 0; j < 6; ++j)
#pragma unroll
        for (int tm = 0; tm < 2; ++tm)
#pragma unroll
            for (int tn = 0; tn < 2; ++tn)
#pragma unroll
                for (int rr = 0; rr < 4; ++rr) {
                    int srow = sbase + wm * 32 + tm * 16 + drow + rr;
                    int col = j * 64 + wn * 32 + tn * 16 + dcol;
                    int hh = col >> 6, d = col & 63;
                    vb[(((size_t)bb * H_ + hh) * S_ + srow) * DH_ + d] = f2bf(accv[j][tm][tn][rr]);
                }
}

// ---------------------------------------------------------------------------
// K5: scatter — one block per (b,h), all 4096 tokens, LDS accumulate,
// NON-atomic global writeout (no memset needed, no global atomics)
// ---------------------------------------------------------------------------
__global__ __launch_bounds__(256) void scatter_kernel(const unsigned short* __restrict__ vb,
                                                      const unsigned int* __restrict__ idx,
                                                      float* __restrict__ acc,
                                                      unsigned int* __restrict__ cnt) {
    __shared__ float accs[N_ * 65];
    __shared__ unsigned int cnts[N_];
    int tid = threadIdx.x;
    int h = blockIdx.x, b = blockIdx.y;
    for (int i = tid; i < N_ * 65; i += 256) accs[i] = 0.f;
    if (tid < N_) cnts[tid] = 0u;
    __syncthreads();
    const unsigned int* idxp = idx + (size_t)(b * H_ + h) * S_;
    const unsigned short* vbp = vb + (size_t)(b * H_ + h) * S_ * DH_;
#pragma unroll 2
    for (int it = 0; it < 16; ++it) {
        int s = it * 256 + tid;
        unsigned g = idxp[s];
        const unsigned short* vrow = vbp + (size_t)s * DH_;
        atomicAdd(&cnts[g], 1u);
#pragma unroll
        for (int jj = 0; jj < 16; ++jj) {
            int c4 = ((jj + (tid & 15)) & 15) * 4;
            ushort4 v = *(const ushort4*)(vrow + c4);
            atomicAdd(&accs[g * 65 + c4 + 0], bf2f(v.x));
            atomicAdd(&accs[g * 65 + c4 + 1], bf2f(v.y));
            atomicAdd(&accs[g * 65 + c4 + 2], bf2f(v.z));
            atomicAdd(&accs[g * 65 + c4 + 3], bf2f(v.w));
        }
    }
    __syncthreads();
    for (int i = tid; i < N_ * DH_; i += 256) {
        int g = i >> 6, d = i & 63;
        acc[((size_t)(b * H_ + h) * N_ + g) * DH_ + d] = accs[g * 65 + d];
    }
    if (tid < N_) cnt[(size_t)(b * H_ + h) * N_ + tid] = cnts[tid];
}

// ---------------------------------------------------------------------------
// K6: out[b,n,j] = sum_c (acc[b,h,n,d]/(cnt+1)) * Wp[j,c] + bp[j]
// ---------------------------------------------------------------------------
__global__ __launch_bounds__(384) void out_kernel(const float* __restrict__ acc,
                                                  const unsigned int* __restrict__ cnt,
                                                  const float* __restrict__ Wp,
                                                  const float* __restrict__ bp,
                                                  float* __restrict__ out) {
    __shared__ float vals[C_];
    int bn = blockIdx.x;
    int b = bn >> 6, n = bn & 63;
    int t = threadIdx.x;
    int h = t >> 6, d = t & 63;
    size_t gi = (size_t)(b * H_ + h) * N_ + n;
    vals[t] = acc[gi * DH_ + d] / ((float)cnt[gi] + 1.0f);
    __syncthreads();
    const float4* w4 = (const float4*)(Wp + (size_t)t * C_);
    const float4* v4 = (const float4*)vals;
    float s = bp[t];
#pragma unroll 8
    for (int i = 0; i < C_ / 4; ++i) {
        float4 a = v4[i]; float4 w = w4[i];
        s += a.x * w.x + a.y * w.y + a.z * w.z + a.w * w.w;
    }
    out[(size_t)bn * C_ + t] = s;
}

// ---------------------------------------------------------------------------
extern "C" void kernel_launch(void* const* d_in, const int* in_sizes, int n_in,
                              void* d_out, int out_size, void* d_ws, size_t ws_size,
                              hipStream_t stream) {
    (void)in_sizes; (void)n_in; (void)out_size; (void)ws_size;
    const float* query = (const float*)d_in[0];
    const float* key   = (const float*)d_in[1];
    const float* Wq    = (const float*)d_in[2];
    const float* Wk    = (const float*)d_in[3];
    const float* Wv    = (const float*)d_in[4];
    const float* Wp    = (const float*)d_in[5];
    const float* bp    = (const float*)d_in[6];
    float* out = (float*)d_out;

    char* ws = (char*)d_ws;
    size_t off = 0;
    unsigned short* vb   = (unsigned short*)(ws + off); off += (size_t)B_ * S_ * C_ * 2;      // head-major [B,H,S,DH]
    unsigned short* khi  = (unsigned short*)(ws + off); off += (size_t)B_ * S_ * C_ * 2;
    unsigned short* klo  = (unsigned short*)(ws + off); off += (size_t)B_ * S_ * C_ * 2;
    float* qk            = (float*)(ws + off);          off += (size_t)B_ * H_ * N_ * C_ * 4;
    unsigned short* qkhi = (unsigned short*)(ws + off); off += (size_t)B_ * H_ * N_ * C_ * 2;
    unsigned short* qklo = (unsigned short*)(ws + off); off += (size_t)B_ * H_ * N_ * C_ * 2;
    unsigned int* idx    = (unsigned int*)(ws + off);   off += (size_t)B_ * H_ * S_ * 4;
    unsigned short* wvb  = (unsigned short*)(ws + off); off += (size_t)C_ * C_ * 2;
    float* acc           = (float*)(ws + off);          off += (size_t)B_ * H_ * N_ * DH_ * 4;
    unsigned int* cnt    = (unsigned int*)(ws + off);   off += (size_t)B_ * H_ * N_ * 4;
    unsigned int* fcnt   = (unsigned int*)(ws + off);   off += 256;
    unsigned int* flist  = (unsigned int*)(ws + off);   off += (size_t)LISTCAP * 4;

    hipMemsetAsync(fcnt, 0, 256, stream);   // only the flag counter needs zeroing

    prep_kernel<<<12360, 256, 0, stream>>>(key, Wv, khi, klo, wvb);
    qk_fused_kernel<<<dim3(N_ / 8, B_), 384, 0, stream>>>(query, Wq, Wk, qk, qkhi, qklo);
    attn_kernel<<<dim3(S_ / 128, H_, B_), 256, 0, stream>>>(qkhi, qklo, khi, klo, idx, fcnt, flist);
    vproj_kernel<<<B_ * S_ / 64, 256, 0, stream>>>(khi, wvb, vb);
    fixup_kernel<<<256, 256, 0, stream>>>(qk, key, flist, fcnt, idx);
    scatter_kernel<<<dim3(H_, B_), 256, 0, stream>>>(vb, idx, acc, cnt);
    out_kernel<<<B_ * N_, 384, 0, stream>>>(acc, cnt, Wp, bp, out);
}